// Round 1
// baseline (266.068 us; speedup 1.0000x reference)
//
#include <hip/hip_runtime.h>
#include <hip/hip_bf16.h>

typedef short s16x8 __attribute__((ext_vector_type(8)));
typedef float f32x4 __attribute__((ext_vector_type(4)));

#define NB 2
#define NSEQ 2048
#define NHID 896
#define NHQ 14
#define NHKV 2
#define HD 64
#define NROW (NB*NSEQ)     // 4096
#define NCAT 2048          // 896 Q | 128 K | 128 V | 896 gate

__device__ __forceinline__ float bf2f(unsigned short s){
  union { float f; unsigned u; } v; v.u = ((unsigned)s) << 16; return v.f;
}
__device__ __forceinline__ short f2bf(float f){
  union { float f; unsigned u; } v; v.f = f;
  unsigned u = v.u + 0x7fffu + ((v.u >> 16) & 1u);
  return (short)(u >> 16);
}

// ---------------- packing kernels ----------------

__global__ void pack_x_kernel(const float* __restrict__ x, short* __restrict__ xb, int n){
  int i = blockIdx.x*256 + threadIdx.x;
  if(i < n) xb[i] = f2bf(x[i]);
}

// WcatT[c][k] = W(k, c) for concatenated [Wq|Wk|Wv|Wg] columns, bf16
__global__ void pack_wcat_kernel(const float* __restrict__ Wq, const float* __restrict__ Wk,
                                 const float* __restrict__ Wv, const float* __restrict__ Wg,
                                 short* __restrict__ WcatT){
  int t = blockIdx.x*256 + threadIdx.x;
  if(t >= NCAT*NHID) return;
  int k = t % NHID, c = t / NHID;
  float v;
  if(c < 896)       v = Wq[k*896 + c];
  else if(c < 1024) v = Wk[k*128 + (c-896)];
  else if(c < 1152) v = Wv[k*128 + (c-1024)];
  else              v = Wg[k*896 + (c-1152)];
  WcatT[t] = f2bf(v);
}

__global__ void pack_wo_kernel(const float* __restrict__ Wo, short* __restrict__ WoT){
  int t = blockIdx.x*256 + threadIdx.x;
  if(t >= NHID*NHID) return;
  int k = t % NHID, c = t / NHID;
  WoT[t] = f2bf(Wo[k*896 + c]);
}

__global__ void rope_table_kernel(const int* __restrict__ pos, float* __restrict__ ct,
                                  float* __restrict__ st){
  int t = blockIdx.x*256 + threadIdx.x;
  if(t >= NROW*32) return;
  int i = t & 31, rn = t >> 5;
  float p = (float)pos[rn];
  float inv = powf(1.0e6f, -(float)i * (1.0f/32.0f));
  float a = p * inv;
  ct[t] = cosf(a);
  st[t] = sinf(a);
}

// V [bh][n][d] -> VbT [bh][d][n]  (LDS tiled transpose, bf16)
__global__ __launch_bounds__(256) void transpose_v_kernel(const short* __restrict__ Vb,
                                                          short* __restrict__ VbT){
  __shared__ short t[64][66];
  int bh = blockIdx.y;           // 0..3
  int n0 = blockIdx.x * 64;      // 32 tiles
  int tid = threadIdx.x;
  #pragma unroll
  for(int it=0; it<2; ++it){
    int idx = it*256 + tid;
    int r = idx >> 3, c0 = (idx & 7)*8;
    s16x8 v = *(const s16x8*)(Vb + ((long)bh*NSEQ + n0 + r)*HD + c0);
    #pragma unroll
    for(int e=0;e<8;e++) t[r][c0+e] = v[e];
  }
  __syncthreads();
  #pragma unroll
  for(int it=0; it<2; ++it){
    int idx = it*256 + tid;
    int d = idx >> 3, k0 = (idx & 7)*8;
    s16x8 o;
    #pragma unroll
    for(int e=0;e<8;e++) o[e] = t[k0+e][d];
    *(s16x8*)(VbT + ((long)bh*HD + d)*NSEQ + n0 + k0) = o;
  }
}

// ---------------- GEMM (bf16 MFMA), EPI=0: QKVG epilogue, EPI=1: plain f32 out ----------------

template<int EPI>
__global__ __launch_bounds__(256)
void gemm_kernel(const short* __restrict__ A, const short* __restrict__ Bt,
                 int M, int Ncols, int K,
                 const float* __restrict__ bq, const float* __restrict__ bk,
                 const float* __restrict__ bv,
                 const float* __restrict__ ct, const float* __restrict__ st,
                 short* __restrict__ Qb, short* __restrict__ Kb, short* __restrict__ Vb,
                 short* __restrict__ gateb, float* __restrict__ outp)
{
  int tid = threadIdx.x;
  int w = tid >> 6, l = tid & 63;
  int wm = w >> 1, wn = w & 1;
  int row0 = blockIdx.y*128 + wm*64;
  int col0 = blockIdx.x*128 + wn*64;
  int lo = l & 15, hi = l >> 4;

  f32x4 acc[4][4];
  #pragma unroll
  for(int mi=0;mi<4;mi++)
    #pragma unroll
    for(int ni=0;ni<4;ni++) acc[mi][ni] = (f32x4){0.f,0.f,0.f,0.f};

  const short* aB = A  + (long)(row0 + lo)*K + 8*hi;
  const short* bB = Bt + (long)(col0 + lo)*K + 8*hi;
  #pragma unroll 2
  for(int k0=0; k0<K; k0+=32){
    s16x8 af[4], bf[4];
    #pragma unroll
    for(int mi=0;mi<4;mi++) af[mi] = *(const s16x8*)(aB + (long)(16*mi)*K + k0);
    #pragma unroll
    for(int ni=0;ni<4;ni++) bf[ni] = *(const s16x8*)(bB + (long)(16*ni)*K + k0);
    #pragma unroll
    for(int mi=0;mi<4;mi++)
      #pragma unroll
      for(int ni=0;ni<4;ni++)
        acc[mi][ni] = __builtin_amdgcn_mfma_f32_16x16x32_bf16(af[mi], bf[ni], acc[mi][ni], 0,0,0);
  }

  if(EPI == 1){
    #pragma unroll
    for(int mi=0;mi<4;mi++)
      #pragma unroll
      for(int ni=0;ni<4;ni++)
        #pragma unroll
        for(int rg=0;rg<4;rg++){
          int r = row0 + 16*mi + 4*hi + rg;
          int c = col0 + lo + 16*ni;
          outp[(long)r*Ncols + c] = acc[mi][ni][rg];
        }
  } else {
    int region = (col0 < 896) ? 0 : (col0 < 1024) ? 1 : (col0 < 1152) ? 2 : 3;
    for(int mi=0;mi<4;mi++){
      for(int rg=0;rg<4;rg++){
        int r = row0 + 16*mi + 4*hi + rg;
        int b = r >> 11, n = r & 2047;
        if(region <= 1){
          // RoPE pair: acc[][ni] (d<32) with acc[][ni+2] (d+32), same head
          #pragma unroll
          for(int ni=0;ni<2;ni++){
            int c  = col0 + lo + 16*ni;
            int cb = (region==0) ? c : (c-896);
            int h = cb >> 6, dlo = cb & 63;           // dlo < 32
            float bl = (region==0) ? bq[c]    : bk[cb];
            float bh = (region==0) ? bq[c+32] : bk[cb+32];
            float ylo = acc[mi][ni  ][rg] + bl;
            float yhi = acc[mi][ni+2][rg] + bh;
            float cs = ct[r*32 + dlo];
            float sn = st[r*32 + dlo];
            float olo = ylo*cs - yhi*sn;
            float ohi = yhi*cs + ylo*sn;
            if(region==0){
              long base = ((long)(b*NHQ + h)*NSEQ + n)*HD;
              Qb[base + dlo]      = f2bf(olo);
              Qb[base + dlo + 32] = f2bf(ohi);
            } else {
              long base = ((long)(b*NHKV + h)*NSEQ + n)*HD;
              Kb[base + dlo]      = f2bf(olo);
              Kb[base + dlo + 32] = f2bf(ohi);
            }
          }
        } else if(region == 2){
          #pragma unroll
          for(int ni=0;ni<4;ni++){
            int c = col0 + lo + 16*ni;
            int cv = c - 1024;
            int h = cv >> 6, d = cv & 63;
            float y = acc[mi][ni][rg] + bv[cv];
            Vb[((long)(b*NHKV + h)*NSEQ + n)*HD + d] = f2bf(y);
          }
        } else {
          #pragma unroll
          for(int ni=0;ni<4;ni++){
            int c = col0 + lo + 16*ni;
            int cg = c - 1152;
            float y = acc[mi][ni][rg];
            gateb[(long)r*NHID + cg] = f2bf(1.0f/(1.0f + __expf(-y)));
          }
        }
      }
    }
  }
}

// ---------------- fused causal GQA flash attention ----------------

__global__ __launch_bounds__(256)
void attn_kernel(const short* __restrict__ Qb, const short* __restrict__ Kb,
                 const short* __restrict__ VbT, const short* __restrict__ gateb,
                 short* __restrict__ Og)
{
  __shared__ __align__(16) short Kl[64][72];   // [key][d]
  __shared__ __align__(16) short Vt[64][72];   // [d][key]
  __shared__ __align__(16) short Pl[4][16][72];// per-wave P [q][key]

  int bid = blockIdx.x;
  int qt = bid & 31;
  int hq = (bid >> 5) % 14;
  int b  = bid / (32*14);
  int kv = hq / 7;
  int tid = threadIdx.x, w = tid >> 6, l = tid & 63, lo = l & 15, hi = l >> 4;

  const short* qptr = Qb + ((long)(b*NHQ + hq)*NSEQ + qt*64 + w*16 + lo)*HD + 8*hi;
  s16x8 qf0 = *(const s16x8*)(qptr);
  s16x8 qf1 = *(const s16x8*)(qptr + 32);

  f32x4 o[4];
  #pragma unroll
  for(int ni=0;ni<4;ni++) o[ni] = (f32x4){0.f,0.f,0.f,0.f};
  float m[4], lsum[4];
  #pragma unroll
  for(int rg=0;rg<4;rg++){ m[rg] = -__builtin_inff(); lsum[rg] = 0.f; }

  const short* kbase = Kb  + (long)(b*NHKV + kv)*NSEQ*HD;
  const short* vtb   = VbT + (long)(b*NHKV + kv)*HD*NSEQ;

  for(int j=0; j<=qt; ++j){
    __syncthreads();
    #pragma unroll
    for(int it=0; it<2; ++it){
      int idx = it*256 + tid;
      int r = idx >> 3, ch = idx & 7;
      s16x8 kk = *(const s16x8*)(kbase + (long)(j*64 + r)*HD + ch*8);
      *(s16x8*)(&Kl[r][ch*8]) = kk;
      s16x8 vv = *(const s16x8*)(vtb + (long)r*NSEQ + j*64 + ch*8);   // r = d
      *(s16x8*)(&Vt[r][ch*8]) = vv;
    }
    __syncthreads();

    // S = Q K^T  (rows=q, cols=key)
    f32x4 s[4];
    #pragma unroll
    for(int ni=0;ni<4;ni++) s[ni] = (f32x4){0.f,0.f,0.f,0.f};
    #pragma unroll
    for(int ni=0;ni<4;ni++){
      s16x8 kf = *(const s16x8*)(&Kl[lo + 16*ni][8*hi]);
      s[ni] = __builtin_amdgcn_mfma_f32_16x16x32_bf16(qf0, kf, s[ni], 0,0,0);
    }
    #pragma unroll
    for(int ni=0;ni<4;ni++){
      s16x8 kf = *(const s16x8*)(&Kl[lo + 16*ni][32 + 8*hi]);
      s[ni] = __builtin_amdgcn_mfma_f32_16x16x32_bf16(qf1, kf, s[ni], 0,0,0);
    }

    if(j == qt){
      #pragma unroll
      for(int ni=0;ni<4;ni++)
        #pragma unroll
        for(int rg=0;rg<4;rg++){
          int key = lo + 16*ni;
          int q   = w*16 + 4*hi + rg;
          float sv = s[ni][rg]*0.125f;
          s[ni][rg] = (key > q) ? -__builtin_inff() : sv;
        }
    } else {
      #pragma unroll
      for(int ni=0;ni<4;ni++)
        #pragma unroll
        for(int rg=0;rg<4;rg++) s[ni][rg] *= 0.125f;
    }

    float pm[4];
    #pragma unroll
    for(int rg=0;rg<4;rg++)
      pm[rg] = fmaxf(fmaxf(s[0][rg], s[1][rg]), fmaxf(s[2][rg], s[3][rg]));
    #pragma unroll
    for(int off=1; off<16; off<<=1)
      #pragma unroll
      for(int rg=0;rg<4;rg++)
        pm[rg] = fmaxf(pm[rg], __shfl_xor(pm[rg], off, 64));

    float fac[4];
    #pragma unroll
    for(int rg=0;rg<4;rg++){
      float mn = fmaxf(m[rg], pm[rg]);
      fac[rg] = __expf(m[rg] - mn);
      m[rg] = mn;
    }

    float rs[4] = {0.f,0.f,0.f,0.f};
    #pragma unroll
    for(int ni=0;ni<4;ni++)
      #pragma unroll
      for(int rg=0;rg<4;rg++){
        float p = __expf(s[ni][rg] - m[rg]);
        s[ni][rg] = p;
        rs[rg] += p;
      }
    #pragma unroll
    for(int off=1; off<16; off<<=1)
      #pragma unroll
      for(int rg=0;rg<4;rg++)
        rs[rg] += __shfl_xor(rs[rg], off, 64);

    #pragma unroll
    for(int rg=0;rg<4;rg++) lsum[rg] = lsum[rg]*fac[rg] + rs[rg];
    #pragma unroll
    for(int ni=0;ni<4;ni++)
      #pragma unroll
      for(int rg=0;rg<4;rg++) o[ni][rg] *= fac[rg];

    // P -> LDS (C-layout -> A-frag layout round trip)
    #pragma unroll
    for(int ni=0;ni<4;ni++)
      #pragma unroll
      for(int rg=0;rg<4;rg++)
        Pl[w][4*hi+rg][lo+16*ni] = f2bf(s[ni][rg]);

    {
      s16x8 pf0 = *(const s16x8*)(&Pl[w][lo][8*hi]);
      #pragma unroll
      for(int ni=0;ni<4;ni++){
        s16x8 vf = *(const s16x8*)(&Vt[lo+16*ni][8*hi]);
        o[ni] = __builtin_amdgcn_mfma_f32_16x16x32_bf16(pf0, vf, o[ni], 0,0,0);
      }
      s16x8 pf1 = *(const s16x8*)(&Pl[w][lo][32 + 8*hi]);
      #pragma unroll
      for(int ni=0;ni<4;ni++){
        s16x8 vf = *(const s16x8*)(&Vt[lo+16*ni][32 + 8*hi]);
        o[ni] = __builtin_amdgcn_mfma_f32_16x16x32_bf16(pf1, vf, o[ni], 0,0,0);
      }
    }
  }

  float inv[4];
  #pragma unroll
  for(int rg=0;rg<4;rg++) inv[rg] = 1.0f/lsum[rg];
  #pragma unroll
  for(int ni=0;ni<4;ni++)
    #pragma unroll
    for(int rg=0;rg<4;rg++){
      int n = qt*64 + w*16 + 4*hi + rg;
      int d = lo + 16*ni;
      float ov = o[ni][rg]*inv[rg];
      long idx = ((long)(b*NSEQ + n))*NHID + hq*HD + d;
      float g = bf2f((unsigned short)gateb[idx]);
      Og[idx] = f2bf(ov*g);
    }
}

// ---------------- launch ----------------

extern "C" void kernel_launch(void* const* d_in, const int* in_sizes, int n_in,
                              void* d_out, int out_size, void* d_ws, size_t ws_size,
                              hipStream_t stream)
{
  const float* hs  = (const float*)d_in[0];
  const int*   pos = (const int*)d_in[1];
  const float* Wq  = (const float*)d_in[2];
  const float* bq  = (const float*)d_in[3];
  const float* Wk  = (const float*)d_in[4];
  const float* bk  = (const float*)d_in[5];
  const float* Wv  = (const float*)d_in[6];
  const float* bv  = (const float*)d_in[7];
  const float* Wg  = (const float*)d_in[8];
  const float* Wo  = (const float*)d_in[9];
  float* out = (float*)d_out;

  char* p = (char*)d_ws;
  short* Xb    = (short*)p; p += (size_t)NROW*NHID*2;
  short* WcatT = (short*)p; p += (size_t)NCAT*NHID*2;
  short* WoT   = (short*)p; p += (size_t)NHID*NHID*2;
  float* ct    = (float*)p; p += (size_t)NROW*32*4;
  float* st    = (float*)p; p += (size_t)NROW*32*4;
  short* Qb    = (short*)p; p += (size_t)NB*NHQ*NSEQ*HD*2;
  short* Kb    = (short*)p; p += (size_t)NB*NHKV*NSEQ*HD*2;
  short* Vb    = (short*)p; p += (size_t)NB*NHKV*NSEQ*HD*2;
  short* VbT   = (short*)p; p += (size_t)NB*NHKV*NSEQ*HD*2;
  short* gateb = (short*)p; p += (size_t)NROW*NHID*2;
  short* Og    = (short*)p; p += (size_t)NROW*NHID*2;

  pack_x_kernel<<<(NROW*NHID+255)/256, 256, 0, stream>>>(hs, Xb, NROW*NHID);
  pack_wcat_kernel<<<(NCAT*NHID+255)/256, 256, 0, stream>>>(Wq, Wk, Wv, Wg, WcatT);
  pack_wo_kernel<<<(NHID*NHID+255)/256, 256, 0, stream>>>(Wo, WoT);
  rope_table_kernel<<<(NROW*32+255)/256, 256, 0, stream>>>(pos, ct, st);

  gemm_kernel<0><<<dim3(NCAT/128, NROW/128), 256, 0, stream>>>(
      Xb, WcatT, NROW, NCAT, NHID, bq, bk, bv, ct, st, Qb, Kb, Vb, gateb, nullptr);

  transpose_v_kernel<<<dim3(NSEQ/64, NB*NHKV), 256, 0, stream>>>(Vb, VbT);

  attn_kernel<<<NB*NHQ*(NSEQ/64), 256, 0, stream>>>(Qb, Kb, VbT, gateb, Og);

  gemm_kernel<1><<<dim3(NHID/128, NROW/128), 256, 0, stream>>>(
      Og, WoT, NROW, NHID, NHID, nullptr, nullptr, nullptr, nullptr, nullptr,
      nullptr, nullptr, nullptr, nullptr, out);
}